// Round 15
// baseline (186.214 us; speedup 1.0000x reference)
//
#include <hip/hip_runtime.h>
#include <hip/hip_bf16.h>

// Problem constants
#define B_  2
#define N_  2048
#define D_  1024
#define H_  16
#define DH_ 64
#define BN_ (B_*N_)   // 4096 rows total

typedef __attribute__((ext_vector_type(8))) short short8;    // 8 bf16 (K=16/32 A/B frag)
typedef __attribute__((ext_vector_type(4))) float f32x4;     // 16x16 C/D frag
typedef __attribute__((ext_vector_type(16))) float f32x16;   // 32x32 C/D frag
typedef __attribute__((ext_vector_type(4))) unsigned int uint4v;

typedef __attribute__((address_space(3))) unsigned int lds_u32_t;
typedef const __attribute__((address_space(1))) unsigned int glb_u32_t;

// async global->LDS, 16B per lane; LDS dst = (wave-uniform base) + lane*16
__device__ __forceinline__ void async_load16(const unsigned short* g, unsigned short* l) {
    __builtin_amdgcn_global_load_lds((glb_u32_t*)g, (lds_u32_t*)l, 16, 0, 0);
}

__device__ __forceinline__ unsigned short f2bf(float f) {
    __hip_bfloat16 h = __float2bfloat16(f);
    return *reinterpret_cast<unsigned short*>(&h);
}

// pack bf16(a) low16 | bf16(b) high16; round-half-up + one v_perm_b32
__device__ __forceinline__ unsigned int pkbf(float a, float b) {
    unsigned int ua = __float_as_uint(a) + 0x8000u;
    unsigned int ub = __float_as_uint(b) + 0x8000u;
    return __builtin_amdgcn_perm(ub, ua, 0x07060302);
}

#if __has_builtin(__builtin_amdgcn_exp2f)
#define EXP2(x) __builtin_amdgcn_exp2f(x)
#else
#define EXP2(x) exp2f(x)
#endif

// softmax scale folded into Q projection: 1/sqrt(DH) * log2(e)
#define QSCL 0.1803368801111204f

// ---------------------------------------------------------------------------
// Kernel 1: cast fp32 -> bf16 for x, Wq, Wk, Wv, Wo (one fused launch)
// ---------------------------------------------------------------------------
__global__ __launch_bounds__(256) void cast_kernel(
    const float* __restrict__ x,  const float* __restrict__ wq,
    const float* __restrict__ wk, const float* __restrict__ wv,
    const float* __restrict__ wo,
    unsigned short* __restrict__ xb,  unsigned short* __restrict__ wqb,
    unsigned short* __restrict__ wkb, unsigned short* __restrict__ wvb,
    unsigned short* __restrict__ wob)
{
    const size_t NX = (size_t)BN_ * D_;   // 4194304
    const size_t NW = (size_t)D_ * D_;    // 1048576 (pow2)
    size_t i = ((size_t)blockIdx.x * 256 + threadIdx.x) * 4;
    const float* src; unsigned short* dst; size_t off;
    if (i < NX) { src = x; dst = xb; off = i; }
    else {
        size_t j = (i - NX) >> 20;          // which W
        off = (i - NX) & (NW - 1);
        src = (j == 0) ? wq : (j == 1) ? wk : (j == 2) ? wv : wo;
        dst = (j == 0) ? wqb : (j == 1) ? wkb : (j == 2) ? wvb : wob;
    }
    float4 v = *(const float4*)(src + off);
    ushort4 o;
    o.x = f2bf(v.x); o.y = f2bf(v.y); o.z = f2bf(v.z); o.w = f2bf(v.w);
    *(ushort4*)(dst + off) = o;
}

// XCD swizzle for 16x64 grids (nwg=1024): flat = y*16+x dispatches round-robin
// to XCD flat%8. Map s = (flat&7)*128 + (flat>>3); bx = s>>6, by = s&63
// (bijective: s = bx*64+by). XCD k owns bx in {2k,2k+1} x all by ->
// W footprint 2 panels (resident), A streamed.
__device__ __forceinline__ void xcd_swz16(int& bx, int& by) {
    int flat = blockIdx.y * 16 + blockIdx.x;
    int s = (flat & 7) * 128 + (flat >> 3);
    bx = s >> 6; by = s & 63;
}

// ---------------------------------------------------------------------------
// Kernel 2 (R15): FUSED QKV, BN 128->64 for 2x occupancy. R14 ledger: qkv
// ~50us at 2 blocks/CU (56KB LDS) — lockstep-latency-bound; every occupancy
// boost this session paid (R9 -13us, R13 -9us), every ILP move was null
// (R8 dbuf, R14 prefetch). Now: LDS 8+3x8 = 32KB -> 4 blocks/CU, grid
// (16,64) = 1024 blocks, 4 waves/SIMD. Per-wave per-step: 24 MFMA / 8 loads
// (ratio better than R9's 16/6). Each wave stages exactly the B-rows it
// consumes (wave*16..+15); barrier still covers the shared x tile.
// Epilogues: R11/R12-verified LDS-stage patterns scaled to 64 cols.
// ---------------------------------------------------------------------------
__global__ __launch_bounds__(256, 4) void qkv_fused(
    const unsigned short* __restrict__ xb,
    const unsigned short* __restrict__ wqb, const unsigned short* __restrict__ wkb,
    const unsigned short* __restrict__ wvb,
    const float* __restrict__ bq, const float* __restrict__ bk, const float* __restrict__ bv,
    unsigned short* __restrict__ q, unsigned short* __restrict__ k, unsigned short* __restrict__ vt)
{
    __shared__ __align__(16) unsigned short As[64 * 64];   // 8 KB  x tile
    __shared__ __align__(16) unsigned short Bq[64 * 64];   // 8 KB  Wq tile / Q stage
    __shared__ __align__(16) unsigned short Bk[64 * 64];   // 8 KB  Wk tile / K stage
    __shared__ __align__(16) unsigned short Bv[64 * 64];   // 8 KB  Wv tile / V^T stage

    const int tid  = threadIdx.x;
    const int lane = tid & 63;
    const int wave = tid >> 6;
    const int l15 = lane & 15, quad = lane >> 4;

    int bx, by; xcd_swz16(bx, by);
    const int row0 = by * 64, col0 = bx * 64;

    const int srow = lane >> 3, scb = lane & 7;

    f32x4 aq[4] = {}, ak[4] = {}, av[4] = {};

    for (int k0 = 0; k0 < D_; k0 += 64) {
        __syncthreads();
#pragma unroll
        for (int cc = 0; cc < 2; ++cc) {          // 8 chunks per 64x64 tile
            int c  = wave * 2 + cc;
            int lr = c * 8 + srow;                // 0..63
            int gcol = k0 + ((scb ^ (lr & 7)) * 8);
            async_load16(xb + (size_t)(row0 + lr) * D_ + gcol, As + c * 512);
            size_t woff = (size_t)(col0 + lr) * D_ + gcol;
            async_load16(wqb + woff, Bq + c * 512);
            async_load16(wkb + woff, Bk + c * 512);
            async_load16(wvb + woff, Bv + c * 512);
        }
        __syncthreads();

#pragma unroll
        for (int kf = 0; kf < 2; ++kf) {
            const int swz = ((kf * 4 + quad) ^ (l15 & 7)) * 8;
            short8 af[4];
#pragma unroll
            for (int mi = 0; mi < 4; mi++)
                af[mi] = *(const short8*)(&As[(mi * 16 + l15) * 64 + swz]);
            const int boff = (wave * 16 + l15) * 64 + swz;
            short8 fq = *(const short8*)(&Bq[boff]);
            short8 fk = *(const short8*)(&Bk[boff]);
            short8 fv = *(const short8*)(&Bv[boff]);
#pragma unroll
            for (int mi = 0; mi < 4; mi++) {
                aq[mi] = __builtin_amdgcn_mfma_f32_16x16x32_bf16(af[mi], fq, aq[mi], 0, 0, 0);
                ak[mi] = __builtin_amdgcn_mfma_f32_16x16x32_bf16(af[mi], fk, ak[mi], 0, 0, 0);
                av[mi] = __builtin_amdgcn_mfma_f32_16x16x32_bf16(af[mi], fv, av[mi], 0, 0, 0);
            }
        }
    }

    // ---- merged epilogues: scatter to disjoint LDS regions, then coop write
    __syncthreads();   // all waves done reading staging LDS
    {
        int c = wave * 16 + l15;                  // local col 0..63
        float biq = bq[col0 + c], bik = bk[col0 + c], biv = bv[col0 + c];
#pragma unroll
        for (int mi = 0; mi < 4; mi++) {
            int r4 = mi * 16 + quad * 4;          // local row, multiple of 4
            // V^T stage: [64c][64r], XOR swz on row within 8-col stripe
            ushort4 pv;
            pv.x = f2bf(av[mi][0] + biv);
            pv.y = f2bf(av[mi][1] + biv);
            pv.z = f2bf(av[mi][2] + biv);
            pv.w = f2bf(av[mi][3] + biv);
            *(ushort4*)(Bv + c * 64 + (r4 ^ ((c & 7) << 3))) = pv;
            // Q (pre-scaled) / K stage: [64r][64c], XOR swz on col
#pragma unroll
            for (int r = 0; r < 4; r++) {
                int row = r4 + r;
                int sc  = c ^ ((row & 7) << 3);
                Bq[row * 64 + sc] = f2bf((aq[mi][r] + biq) * QSCL);
                Bk[row * 64 + sc] = f2bf(ak[mi][r] + bik);
            }
        }
    }
    __syncthreads();
    // coop write: 512 items each; Q/K = 64 rows x 8 col-blocks(16B), 8 lanes
    // = 128B contiguous per row; V^T = 64 cols x 8 row-blocks(16B).
#pragma unroll
    for (int itx = 0; itx < 2; ++itx) {
        int item = itx * 256 + tid;
        int row = item >> 3, cb = item & 7;
        uint4v vq = *(const uint4v*)(Bq + row * 64 + ((cb ^ (row & 7)) * 8));
        *(uint4v*)(q + (size_t)(row0 + row) * D_ + col0 + cb * 8) = vq;
        uint4v vk = *(const uint4v*)(Bk + row * 64 + ((cb ^ (row & 7)) * 8));
        *(uint4v*)(k + (size_t)(row0 + row) * D_ + col0 + cb * 8) = vk;
        int c = item >> 3, rb = item & 7;
        uint4v vv = *(const uint4v*)(Bv + c * 64 + ((rb ^ (c & 7)) * 8));
        *(uint4v*)(vt + (size_t)(col0 + c) * BN_ + row0 + rb * 8) = vv;
    }
}

// ---------------------------------------------------------------------------
// Kernel 4 (R15): output projection, 64x64 tile, grid (16,64) = 1024 blocks
// = 4 blocks/CU (was 512 = 2/CU). fp32 out, 64B-contiguous stores.
// ---------------------------------------------------------------------------
__global__ __launch_bounds__(256, 4) void out_gemm(
    const unsigned short* __restrict__ attn, const unsigned short* __restrict__ wob,
    const float* __restrict__ bo, float* __restrict__ out)
{
    __shared__ __align__(16) unsigned short As[64 * 64];   // 8 KB
    __shared__ __align__(16) unsigned short Bs[64 * 64];   // 8 KB

    const int tid  = threadIdx.x;
    const int lane = tid & 63;
    const int wave = tid >> 6;
    const int l15 = lane & 15, quad = lane >> 4;

    int bx, by; xcd_swz16(bx, by);
    const int row0 = by * 64, col0 = bx * 64;

    const int srow = lane >> 3, scb = lane & 7;

    f32x4 acc[4] = {};

    for (int k0 = 0; k0 < D_; k0 += 64) {
        __syncthreads();
#pragma unroll
        for (int cc = 0; cc < 2; ++cc) {
            int c  = wave * 2 + cc;
            int lr = c * 8 + srow;
            int gcol = k0 + ((scb ^ (lr & 7)) * 8);
            async_load16(attn + (size_t)(row0 + lr) * D_ + gcol, As + c * 512);
            async_load16(wob  + (size_t)(col0 + lr) * D_ + gcol, Bs + c * 512);
        }
        __syncthreads();

#pragma unroll
        for (int kf = 0; kf < 2; ++kf) {
            const int swz = ((kf * 4 + quad) ^ (l15 & 7)) * 8;
            short8 af[4];
#pragma unroll
            for (int mi = 0; mi < 4; mi++)
                af[mi] = *(const short8*)(&As[(mi * 16 + l15) * 64 + swz]);
            short8 bf = *(const short8*)(&Bs[(wave * 16 + l15) * 64 + swz]);
#pragma unroll
            for (int mi = 0; mi < 4; mi++)
                acc[mi] = __builtin_amdgcn_mfma_f32_16x16x32_bf16(af[mi], bf, acc[mi], 0, 0, 0);
        }
    }

    // fp32 out: 16 lanes x 4B = 64B contiguous
    {
        int col = col0 + wave * 16 + l15;
        float bvv = bo[col];
#pragma unroll
        for (int mi = 0; mi < 4; mi++) {
            int row = row0 + mi * 16 + quad * 4;
#pragma unroll
            for (int r = 0; r < 4; r++)
                out[(size_t)(row + r) * D_ + col] = acc[mi][r] + bvv;
        }
    }
}

// ---------------------------------------------------------------------------
// Kernel 3 (R14-frozen): flash attention, in-block KV-split, 8 waves/block,
// per-half double-buffer prefetch. ~52-53us; lockstep-issue-bound (R14
// post-mortem: prefetch null, VALU 47%) — at this structure's floor.
// ---------------------------------------------------------------------------
__global__ __launch_bounds__(512, 4) void attn_kernel(
    const unsigned short* __restrict__ q, const unsigned short* __restrict__ k,
    const unsigned short* __restrict__ vt, unsigned short* __restrict__ o)
{
    __shared__ __align__(16) unsigned short Ks[2][2][64 * 64];   // [half][buf] 32 KB
    __shared__ __align__(16) unsigned short Vs[2][2][64 * 64];   // 32 KB
    __shared__ float Ls[4][32];                                  // 512 B lsum merge

    const int tid = threadIdx.x;
    const int lane = tid & 63, wave = tid >> 6;   // wave 0..7
    const int l31 = lane & 31, kq = lane >> 5;
    const int wlow = wave & 3;                    // row-group 0..3
    const int half = wave >> 2;                   // kv half 0/1
    const int bh = blockIdx.x;
    const int qt = blockIdx.y;
    const int b = bh >> 4, h = bh & 15;

    const unsigned short* qb = q  + (size_t)b * N_ * D_ + h * DH_;
    const unsigned short* kb = k  + (size_t)b * N_ * D_ + h * DH_;
    const unsigned short* vb = vt + (size_t)h * DH_ * BN_ + (size_t)b * N_;

    const int qrow0 = qt * 128 + wlow * 32;

    short8 qf[4];
#pragma unroll
    for (int s = 0; s < 4; s++)
        qf[s] = *(const short8*)(qb + (size_t)(qrow0 + l31) * D_ + s * 16 + kq * 8);

    f32x16 oacc[2] = {};
    float lsum = 0.f;

    const int srow = lane >> 3, scb = lane & 7;
    const int kvoff = half * (N_ / 2);            // 0 or 1024

    auto stage = [&](int bi, int it) {
        const int kv0 = kvoff + it * 64;
#pragma unroll
        for (int cc = 0; cc < 2; ++cc) {
            int c  = wlow * 2 + cc;               // 0..7
            int lr = c * 8 + srow;
            int swz8 = (scb ^ (lr & 7)) * 8;
            async_load16(kb + (size_t)(kv0 + lr) * D_ + swz8,
                         (unsigned short*)Ks[half][bi] + c * 512);
            async_load16(vb + (size_t)lr * BN_ + kv0 + swz8,
                         (unsigned short*)Vs[half][bi] + c * 512);
        }
    };

    stage(0, 0);   // prologue

    const int NIT = 16;                            // 16 tiles per half
    for (int it = 0; it < NIT; ++it) {
        const int cur = it & 1;
        __syncthreads();   // drains vmcnt -> buf[cur] ready; buf[cur^1] free
        if (it + 1 < NIT) stage(cur ^ 1, it + 1);  // prefetch next tile

        const unsigned short* Kc = Ks[half][cur];
        const unsigned short* Vc = Vs[half][cur];

        f32x16 st[2] = {};
        __builtin_amdgcn_s_setprio(1);
#pragma unroll
        for (int s = 0; s < 4; s++) {
#pragma unroll
            for (int mb = 0; mb < 2; mb++) {
                short8 kfr = *(const short8*)((const char*)Kc +
                    (mb * 32 + l31) * 128 + (((2 * s + kq) ^ (l31 & 7)) * 16));
                st[mb] = __builtin_amdgcn_mfma_f32_32x32x16_bf16(
                    kfr, qf[s], st[mb], 0, 0, 0);
            }
        }
        __builtin_amdgcn_s_setprio(0);

#pragma unroll
        for (int mb = 0; mb < 2; mb++) {
            unsigned int pk[8];
#pragma unroll
            for (int g = 0; g < 4; g++) {
                float p0 = EXP2(st[mb][g * 4 + 0]);
                float p1 = EXP2(st[mb][g * 4 + 1]);
                float p2 = EXP2(st[mb][g * 4 + 2]);
                float p3 = EXP2(st[mb][g * 4 + 3]);
                lsum += (p0 + p1) + (p2 + p3);
                pk[2 * g + 0] = pkbf(p0, p1);
                pk[2 * g + 1] = pkbf(p2, p3);
            }
            __builtin_amdgcn_s_setprio(1);
#pragma unroll
            for (int s = 0; s < 2; s++) {
                uint4v fu;
                fu[0] = pk[4 * s + 0]; fu[1] = pk[4 * s + 1];
                fu[2] = pk[4 * s + 2]; fu[3] = pk[4 * s + 3];
                short8 pf = __builtin_bit_cast(short8, fu);
                const int blkA = 4 * mb + 2 * s;
#pragma unroll
                for (int nb = 0; nb < 2; nb++) {
                    const char* vrow = (const char*)Vc + (nb * 32 + l31) * 128;
                    uint2 vlo = *(const uint2*)(vrow + ((blkA       ^ (l31 & 7)) * 16) + kq * 8);
                    uint2 vhi = *(const uint2*)(vrow + (((blkA + 1) ^ (l31 & 7)) * 16) + kq * 8);
                    uint4v vu; vu[0] = vlo.x; vu[1] = vlo.y; vu[2] = vhi.x; vu[3] = vhi.y;
                    short8 vf = __builtin_bit_cast(short8, vu);
                    oacc[nb] = __builtin_amdgcn_mfma_f32_32x32x16_bf16(
                        pf, vf, oacc[nb], 0, 0, 0);
                }
            }
            __builtin_amdgcn_s_setprio(0);
        }
    }

    // ---- in-block pair merge: wave w (lower) + wave w+4 (upper) ----
    __syncthreads();                // all tile reads done -> Ks/Vs reusable
    lsum += __shfl_xor(lsum, 32);   // full row-sum of this wave's kv half

    const int idx = wave & 3;
    float* mrg = ((idx & 2) ? (float*)Vs : (float*)Ks) + (idx & 1) * 2048;

    if (wave >= 4) {
#pragma unroll
        for (int q8 = 0; q8 < 8; ++q8) {
            int nb = q8 >> 2, j = (q8 & 3) * 4;
            f32x4 c;
            c[0] = oacc[nb][j + 0]; c[1] = oacc[nb][j + 1];
            c[2] = oacc[nb][j + 2]; c[3] = oacc[nb][j + 3];
            *(f32x4*)(mrg + (q8 * 64 + lane) * 4) = c;
        }
        if (kq == 0) Ls[wave - 4][l31] = lsum;
    }
    __syncthreads();
    if (wave < 4) {
#pragma unroll
        for (int q8 = 0; q8 < 8; ++q8) {
            int nb = q8 >> 2, j = (q8 & 3) * 4;
            f32x4 r = *(const f32x4*)(mrg + (q8 * 64 + lane) * 4);
            oacc[nb][j + 0] += r[0]; oacc[nb][j + 1] += r[1];
            oacc[nb][j + 2] += r[2]; oacc[nb][j + 3] += r[3];
        }
        lsum += Ls[wave][l31];
    }
    __syncthreads();   // merge reads done before Lt overwrites Ks

    if (wave < 4) {
        float* Lt = (float*)&Ks[0][0][0] + wave * 32;
        if (kq == 0) Lt[l31] = lsum;
        asm volatile("s_waitcnt lgkmcnt(0)" ::: "memory");

#pragma unroll
        for (int g = 0; g < 4; g++)
#pragma unroll
            for (int rr = 0; rr < 4; rr++) {
                int reg = g * 4 + rr;
                float inv = 1.f / Lt[rr + 8 * g + 4 * kq];
                int row = qrow0 + rr + 8 * g + 4 * kq;
                size_t base = ((size_t)b * N_ + row) * D_ + h * DH_;
#pragma unroll
                for (int nb = 0; nb < 2; nb++)
                    o[base + nb * 32 + l31] = f2bf(oacc[nb][reg] * inv);
            }
    }
}

// ---------------------------------------------------------------------------
extern "C" void kernel_launch(void* const* d_in, const int* in_sizes, int n_in,
                              void* d_out, int out_size, void* d_ws, size_t ws_size,
                              hipStream_t stream)
{
    const float* x  = (const float*)d_in[0];
    const float* Wq = (const float*)d_in[1];
    const float* bq = (const float*)d_in[2];
    const float* Wk = (const float*)d_in[3];
    const float* bk = (const float*)d_in[4];
    const float* Wv = (const float*)d_in[5];
    const float* bv = (const float*)d_in[6];
    const float* Wo = (const float*)d_in[7];
    const float* bo = (const float*)d_in[8];
    float* out = (float*)d_out;

    char* ws = (char*)d_ws;
    unsigned short* xb  = (unsigned short*)(ws + 0);         //  8 MB  x bf16
    unsigned short* wqb = (unsigned short*)(ws + 8388608);   //  2 MB
    unsigned short* wkb = (unsigned short*)(ws + 10485760);  //  2 MB
    unsigned short* wvb = (unsigned short*)(ws + 12582912);  //  2 MB
    unsigned short* wob = (unsigned short*)(ws + 14680064);  //  2 MB
    unsigned short* qd  = (unsigned short*)(ws + 16777216);  //  8 MB  Q (pre-scaled)
    unsigned short* kd  = (unsigned short*)(ws + 25165824);  //  8 MB
    unsigned short* vtd = (unsigned short*)(ws + 33554432);  //  8 MB  V^T [D][B*N]
    unsigned short* ad  = (unsigned short*)(ws + 41943040);  //  8 MB  attn out
    // total 48 MB

    cast_kernel<<<8192, 256, 0, stream>>>(x, Wq, Wk, Wv, Wo, xb, wqb, wkb, wvb, wob);
    qkv_fused<<<dim3(16, 64), 256, 0, stream>>>(xb, wqb, wkb, wvb, bq, bk, bv, qd, kd, vtd);
    attn_kernel<<<dim3(32, 16), 512, 0, stream>>>(qd, kd, vtd, ad);
    out_gemm<<<dim3(16, 64), 256, 0, stream>>>(ad, wob, bo, out);
}